// Round 1
// baseline (478.400 us; speedup 1.0000x reference)
//
#include <hip/hip_runtime.h>

// Problem constants
#define CV   34          // C*V channels
#define TTOT 2048        // T
#define NB   512         // batches
#define XB   69632       // x per-batch stride (2*2048*17)
#define XC   34816       // x per-co stride (2048*17)

// Workspace layout (floats)
#define GS_STRIDE 1192                   // per-batch: G (1156) + s0 (34) + pad
#define RB_OFF    (512 * 1192)           // region B offset
#define RB_STRIDE 1040                   // per-batch: Wy bf16 hi/lo planes (1024 f) + cy (16 f)

typedef __attribute__((ext_vector_type(8))) short v8s;   // 8 x bf16 (MFMA A/B frag)
typedef __attribute__((ext_vector_type(4))) float v4f;   // 4 x f32 (MFMA C/D frag)

__device__ __forceinline__ unsigned short f2bf(float f) {
    unsigned int u = __float_as_uint(f);
    u = u + 0x7FFFu + ((u >> 16) & 1u);   // round-to-nearest-even
    return (unsigned short)(u >> 16);
}
__device__ __forceinline__ float bf2f(unsigned short s) {
    return __uint_as_float(((unsigned int)s) << 16);
}

// ---------------------------------------------------------------------------
// K1: per-batch Gram matrix G0 = H0 H0^T (34x34) and row sums s0 (34)
// bf16 hi/lo split MFMA: G = Hh Hh^T + Hh Hl^T + Hl Hh^T  (~fp32 accuracy)
// ---------------------------------------------------------------------------
__global__ __launch_bounds__(256) void k_gram(const float* __restrict__ x,
                                              float* __restrict__ ws) {
    __shared__ unsigned short Hh[48][136];   // 48 rows (3 MFMA row tiles), 128 t + pad
    __shared__ unsigned short Hl[48][136];
    __shared__ float Gpart[4][34][36];
    __shared__ float spart[4][36];

    const int b    = blockIdx.x;
    const int tid  = threadIdx.x;
    const int l    = tid & 63;
    const int w    = tid >> 6;      // wave id 0..3 -> kstep within chunk
    const int row16 = l & 15;
    const int quad  = l >> 4;
    const float* xb = x + (size_t)b * XB;

    v4f accG[3][3];
    v4f accS[3];
    v4f vz = {0.f, 0.f, 0.f, 0.f};
#pragma unroll
    for (int r = 0; r < 3; ++r) {
        accS[r] = vz;
#pragma unroll
        for (int c = 0; c < 3; ++c) accG[r][c] = vz;
    }
    v8s ones;
#pragma unroll
    for (int i = 0; i < 8; ++i) ones[i] = (short)0x3F80;   // bf16 1.0

    for (int ch = 0; ch < 16; ++ch) {        // 16 chunks of 128 t
        __syncthreads();
        // stage chunk: x[b,co,t,v] -> H[co*17+v][t_local], bf16 hi/lo
        for (int co = 0; co < 2; ++co) {
            const float* src = xb + co * XC + ch * 2176;   // 128*17
            for (int j = tid; j < 2176; j += 256) {
                float f = src[j];
                int t = j / 17;
                int v = j - t * 17;
                unsigned short hb = f2bf(f);
                Hh[co * 17 + v][t] = hb;
                Hl[co * 17 + v][t] = f2bf(f - bf2f(hb));
            }
        }
        __syncthreads();
        // wave w handles k-slice [w*32, w*32+32)
        const int koff = w * 32 + quad * 8;
        v8s fh[3], fl4[3];
#pragma unroll
        for (int r = 0; r < 3; ++r) {
            fh[r]  = *(const v8s*)&Hh[r * 16 + row16][koff];
            fl4[r] = *(const v8s*)&Hl[r * 16 + row16][koff];
        }
#pragma unroll
        for (int r = 0; r < 3; ++r) {
#pragma unroll
            for (int c = 0; c < 3; ++c) {
                accG[r][c] = __builtin_amdgcn_mfma_f32_16x16x32_bf16(fh[r],  fh[c],  accG[r][c], 0, 0, 0);
                accG[r][c] = __builtin_amdgcn_mfma_f32_16x16x32_bf16(fh[r],  fl4[c], accG[r][c], 0, 0, 0);
                accG[r][c] = __builtin_amdgcn_mfma_f32_16x16x32_bf16(fl4[r], fh[c],  accG[r][c], 0, 0, 0);
            }
            accS[r] = __builtin_amdgcn_mfma_f32_16x16x32_bf16(fh[r],  ones, accS[r], 0, 0, 0);
            accS[r] = __builtin_amdgcn_mfma_f32_16x16x32_bf16(fl4[r], ones, accS[r], 0, 0, 0);
        }
    }

    // write per-wave partials (D layout: row = quad*4+i, col = lane&15)
#pragma unroll
    for (int r = 0; r < 3; ++r) {
#pragma unroll
        for (int c = 0; c < 3; ++c) {
#pragma unroll
            for (int i = 0; i < 4; ++i) {
                int m = r * 16 + quad * 4 + i;
                int n = c * 16 + row16;
                if (m < 34 && n < 34) Gpart[w][m][n] = accG[r][c][i];
            }
        }
        if (row16 == 0) {
#pragma unroll
            for (int i = 0; i < 4; ++i) {
                int m = r * 16 + quad * 4 + i;
                if (m < 34) spart[w][m] = accS[r][i];
            }
        }
    }
    __syncthreads();
    float* gout = ws + (size_t)b * GS_STRIDE;
    for (int idx = tid; idx < 1156; idx += 256) {
        int m = idx / 34, n = idx - m * 34;
        gout[idx] = Gpart[0][m][n] + Gpart[1][m][n] + Gpart[2][m][n] + Gpart[3][m][n];
    }
    if (tid < 34)
        gout[1156 + tid] = spart[0][tid] + spart[1][tid] + spart[2][tid] + spart[3][tid];
}

// ---------------------------------------------------------------------------
// K2: per-batch affine chain through 3 attention layers + BN-folded head.
// All matmuls are C[i][j] = sum_e L[i][e]*R[j][e] on 36-padded LDS tiles.
// ---------------------------------------------------------------------------
__device__ void mm(float L[][36], float R[][36], float D[][36], int tid) {
    if (tid < 81) {
        int ti = tid / 9, tj = tid - ti * 9;
        int i0 = ti * 4, j0 = tj * 4;
        float acc[4][4] = {};
        for (int e0 = 0; e0 < 36; e0 += 4) {
            float4 lv[4], rv[4];
#pragma unroll
            for (int a = 0; a < 4; ++a) {
                lv[a] = *(const float4*)&L[i0 + a][e0];
                rv[a] = *(const float4*)&R[j0 + a][e0];
            }
#pragma unroll
            for (int a = 0; a < 4; ++a)
#pragma unroll
                for (int c = 0; c < 4; ++c)
                    acc[a][c] += lv[a].x * rv[c].x + lv[a].y * rv[c].y +
                                 lv[a].z * rv[c].z + lv[a].w * rv[c].w;
        }
#pragma unroll
        for (int a = 0; a < 4; ++a)
#pragma unroll
            for (int c = 0; c < 4; ++c)
                D[i0 + a][j0 + c] = acc[a][c];
    }
}

__global__ __launch_bounds__(128) void k_chain(
    const float* __restrict__ wq, const float* __restrict__ bq,
    const float* __restrict__ wk, const float* __restrict__ bk,
    const float* __restrict__ wv, const float* __restrict__ bv,
    const float* __restrict__ w1, const float* __restrict__ b1,
    const float* __restrict__ gamma, const float* __restrict__ beta,
    const float* __restrict__ mean, const float* __restrict__ var,
    float* __restrict__ ws) {
    __shared__ float G0b[36][36], At[36][36], Aq[36][36], Ak[36][36], Av[36][36],
        Avt[36][36], S1[36][36], Sc[36][36], Wq[36][36], Wk[36][36], Wv[36][36];
    __shared__ float s0v[36], a_[36], aq_[36], ak_[36], avv_[36], qs_[36], ks_[36],
        bqv[36], bkv[36], bvv[36], invv[16];

    const int tid = threadIdx.x;
    const int b   = blockIdx.x;
    const float* gsb = ws + (size_t)b * GS_STRIDE;

    for (int i = tid; i < 36 * 36; i += 128) {
        ((float*)G0b)[i] = 0; ((float*)At)[i] = 0; ((float*)Aq)[i] = 0;
        ((float*)Ak)[i] = 0;  ((float*)Av)[i] = 0; ((float*)Avt)[i] = 0;
        ((float*)S1)[i] = 0;  ((float*)Sc)[i] = 0; ((float*)Wq)[i] = 0;
        ((float*)Wk)[i] = 0;  ((float*)Wv)[i] = 0;
    }
    if (tid < 36) {
        s0v[tid] = 0; a_[tid] = 0; aq_[tid] = 0; ak_[tid] = 0; avv_[tid] = 0;
        qs_[tid] = 0; ks_[tid] = 0; bqv[tid] = 0; bkv[tid] = 0; bvv[tid] = 0;
    }
    __syncthreads();
    for (int i = tid; i < 1156; i += 128) {
        int m = i / 34;
        G0b[m][i - m * 34] = gsb[i];
    }
    if (tid < 34) {
        s0v[tid] = gsb[1156 + tid];
        At[tid][tid] = 1.0f;          // A = I (At = A^T)
    }

    for (int lyr = 0; lyr < 3; ++lyr) {
        __syncthreads();
        const float* wql = wq + lyr * 1156;
        const float* wkl = wk + lyr * 1156;
        const float* wvl = wv + lyr * 1156;
        for (int i = tid; i < 1156; i += 128) {
            int m = i / 34, n = i - m * 34;
            Wq[m][n] = wql[i]; Wk[m][n] = wkl[i]; Wv[m][n] = wvl[i];
        }
        if (tid < 34) {
            bqv[tid] = bq[lyr * 34 + tid];
            bkv[tid] = bk[lyr * 34 + tid];
            bvv[tid] = bv[lyr * 34 + tid];
        }
        __syncthreads();
        mm(Wq, At, Aq, tid);   // Aq[o][c] = (wq A)[o][c]
        mm(Wk, At, Ak, tid);
        mm(Wv, At, Av, tid);
        __syncthreads();
        for (int i = tid; i < 1296; i += 128) {
            int m = i / 36, n = i - m * 36;
            Avt[m][n] = Av[n][m];
        }
        if (tid < 34) {
            float x1 = 0, x2 = 0, x3 = 0;
            for (int e = 0; e < 34; ++e) {
                x1 += Wq[tid][e] * a_[e];
                x2 += Wk[tid][e] * a_[e];
                x3 += Wv[tid][e] * a_[e];
            }
            aq_[tid]  = x1 + bqv[tid];
            ak_[tid]  = x2 + bkv[tid];
            avv_[tid] = x3 + bvv[tid];
            float y1 = 0, y2 = 0;
            for (int e = 0; e < 34; ++e) {
                y1 += Aq[tid][e] * s0v[e];
                y2 += Ak[tid][e] * s0v[e];
            }
            qs_[tid] = y1; ks_[tid] = y2;
        }
        __syncthreads();
        mm(Aq, G0b, S1, tid);    // S1 = Aq G0 (G0 symmetric)
        __syncthreads();
        mm(S1, Ak, Sc, tid);     // Sc = Aq G0 Ak^T
        __syncthreads();
        if (tid < 34) {
            const int c = tid;
            const float scale = 0.022097086912079608f;   // 1/sqrt(2048)
            float mx = -1e30f;
            for (int d = 0; d < 34; ++d) {
                float v = (Sc[c][d] + qs_[c] * ak_[d] + aq_[c] * ks_[d] +
                           2048.0f * aq_[c] * ak_[d]) * scale;
                Sc[c][d] = v;
                mx = fmaxf(mx, v);
            }
            float sum = 0;
            for (int d = 0; d < 34; ++d) {
                float e = __expf(Sc[c][d] - mx);
                Sc[c][d] = e;
                sum += e;
            }
            float rs = 1.0f / sum;
            for (int d = 0; d < 34; ++d) Sc[c][d] *= rs;
        }
        __syncthreads();
        mm(Avt, Sc, At, tid);    // At_new[j][c] = sum_d Av[d][j] attn[c][d]
        if (tid < 34) {
            float s = 0;
            for (int d = 0; d < 34; ++d) s += Sc[tid][d] * avv_[d];
            a_[tid] = s;
        }
    }
    __syncthreads();
    // head: Wy = w1 * A3, fold BN
    for (int i = tid; i < 1296; i += 128) {
        int m = i / 36, n = i - m * 36;
        Wq[m][n] = (m < 16 && n < 34) ? w1[m * 34 + n] : 0.0f;
    }
    if (tid < 16) invv[tid] = gamma[tid] * rsqrtf(var[tid] + 1e-5f);
    __syncthreads();
    mm(Wq, At, S1, tid);         // S1[o][c] = Wy
    __syncthreads();
    float* wb = ws + RB_OFF + (size_t)b * RB_STRIDE;
    if (tid < 16) {
        float cy = 0;
        for (int e = 0; e < 34; ++e) cy += Wq[tid][e] * a_[e];
        cy += b1[tid];
        wb[1024 + tid] = (cy - mean[tid]) * invv[tid] + beta[tid];
    }
    unsigned short* wp = (unsigned short*)wb;
    for (int i = tid; i < 1024; i += 128) {
        int o = i >> 6, c = i & 63;
        float vv = (c < 34) ? S1[o][c] * invv[o] : 0.0f;
        unsigned short hb = f2bf(vv);
        wp[i] = hb;
        wp[1024 + i] = f2bf(vv - bf2f(hb));
    }
}

// ---------------------------------------------------------------------------
// K3: out = w2 * leaky(Wy' h0 + cy') + b2, streaming over t via MFMA.
// Block covers 512 t of one batch, 4 chunks of 128 t staged to LDS as h^T.
// ---------------------------------------------------------------------------
__global__ __launch_bounds__(256) void k_out(const float* __restrict__ x,
                                             const float* __restrict__ w2,
                                             const float* __restrict__ b2,
                                             const float* __restrict__ ws,
                                             float* __restrict__ out) {
    __shared__ unsigned short HtH[128][64];   // h^T rows = t, cols = channel (padded 64)
    __shared__ unsigned short HtL[128][64];

    const int tid  = threadIdx.x;
    const int b    = blockIdx.x >> 2;
    const int seg  = (blockIdx.x & 3) * 512;
    const int l    = tid & 63;
    const int w    = tid >> 6;
    const int quad = l >> 4;
    const int col  = l & 15;

    const float* wb = ws + RB_OFF + (size_t)b * RB_STRIDE;
    const unsigned short* wp = (const unsigned short*)wb;
    v8s aH[2], aL[2];   // Wy A-frags: A[m=lane&15][k=quad*8+j], 2 k-steps
#pragma unroll
    for (int ks = 0; ks < 2; ++ks) {
        aH[ks] = *(const v8s*)&wp[col * 64 + ks * 32 + quad * 8];
        aL[ks] = *(const v8s*)&wp[1024 + col * 64 + ks * 32 + quad * 8];
    }
    float cyr[4], w2r[3][4];
#pragma unroll
    for (int i = 0; i < 4; ++i) {
        int o = quad * 4 + i;
        cyr[i] = wb[1024 + o];
#pragma unroll
        for (int p = 0; p < 3; ++p) w2r[p][i] = w2[p * 16 + o];
    }
    float b2r[3] = {b2[0], b2[1], b2[2]};
    const float* xb = x + (size_t)b * XB;

    // zero channel pad cols 34..63 once (fills only touch cols < 34)
    for (int idx = tid; idx < 128 * 30; idx += 256) {
        int t = idx / 30;
        int c = 34 + (idx - t * 30);
        HtH[t][c] = 0;
        HtL[t][c] = 0;
    }

    for (int ch = 0; ch < 4; ++ch) {
        const int t0c = seg + ch * 128;
        __syncthreads();
        for (int co = 0; co < 2; ++co) {
            const float* src = xb + co * XC + t0c * 17;
            for (int j = tid; j < 2176; j += 256) {
                int t = j / 17;
                int v = j - t * 17;
                float f = src[j];
                unsigned short hb = f2bf(f);
                HtH[t][co * 17 + v] = hb;
                HtL[t][co * 17 + v] = f2bf(f - bf2f(hb));
            }
        }
        __syncthreads();
        for (int tt = w; tt < 8; tt += 4) {       // 8 t-tiles of 16, wave-strided
            const int tBase = tt * 16;
            v4f acc = {0.f, 0.f, 0.f, 0.f};
#pragma unroll
            for (int ks = 0; ks < 2; ++ks) {
                v8s bH = *(const v8s*)&HtH[tBase + col][ks * 32 + quad * 8];
                v8s bL = *(const v8s*)&HtL[tBase + col][ks * 32 + quad * 8];
                acc = __builtin_amdgcn_mfma_f32_16x16x32_bf16(aH[ks], bH, acc, 0, 0, 0);
                acc = __builtin_amdgcn_mfma_f32_16x16x32_bf16(aH[ks], bL, acc, 0, 0, 0);
                acc = __builtin_amdgcn_mfma_f32_16x16x32_bf16(aL[ks], bH, acc, 0, 0, 0);
            }
            // epilogue: y -> leaky -> partial w2 dot (4 o's per lane)
            float op[3] = {0, 0, 0};
#pragma unroll
            for (int i = 0; i < 4; ++i) {
                float y = acc[i] + cyr[i];
                float z = (y > 0.f) ? y : 0.01f * y;
#pragma unroll
                for (int p = 0; p < 3; ++p) op[p] += w2r[p][i] * z;
            }
#pragma unroll
            for (int p = 0; p < 3; ++p) {
                op[p] += __shfl_xor(op[p], 16);
                op[p] += __shfl_xor(op[p], 32);
            }
            if (l < 16) {
                int tg = t0c + tBase + l;
#pragma unroll
                for (int p = 0; p < 3; ++p)
                    out[((size_t)b * 3 + p) * 2048 + tg] = op[p] + b2r[p];
            }
        }
    }
}

extern "C" void kernel_launch(void* const* d_in, const int* in_sizes, int n_in,
                              void* d_out, int out_size, void* d_ws, size_t ws_size,
                              hipStream_t stream) {
    const float* x     = (const float*)d_in[0];
    const float* wq    = (const float*)d_in[1];
    const float* bq    = (const float*)d_in[2];
    const float* wk    = (const float*)d_in[3];
    const float* bk    = (const float*)d_in[4];
    const float* wv    = (const float*)d_in[5];
    const float* bv    = (const float*)d_in[6];
    const float* w1    = (const float*)d_in[7];
    const float* b1    = (const float*)d_in[8];
    const float* gamma = (const float*)d_in[9];
    const float* beta  = (const float*)d_in[10];
    const float* mean  = (const float*)d_in[11];
    const float* var   = (const float*)d_in[12];
    const float* w2    = (const float*)d_in[13];
    const float* b2    = (const float*)d_in[14];
    float* ws  = (float*)d_ws;
    float* out = (float*)d_out;

    k_gram<<<dim3(512), dim3(256), 0, stream>>>(x, ws);
    k_chain<<<dim3(512), dim3(128), 0, stream>>>(wq, bq, wk, bk, wv, bv,
                                                 w1, b1, gamma, beta, mean, var, ws);
    k_out<<<dim3(2048), dim3(256), 0, stream>>>(x, w2, b2, ws, out);
}

// Round 2
// 363.135 us; speedup vs baseline: 1.3174x; 1.3174x over previous
//
#include <hip/hip_runtime.h>

// Problem constants
#define CV   34          // C*V channels
#define TTOT 2048        // T
#define NB   512         // batches
#define XB   69632       // x per-batch stride (2*2048*17)
#define XC   34816       // x per-co stride (2048*17)

// Workspace layout (floats)
#define GS_STRIDE 1192                   // per-batch: G (1156) + s0 (34) + pad
#define RB_OFF    (512 * 1192)           // region B offset
#define RB_STRIDE 1040                   // per-batch: Wy bf16 hi/lo planes (1024 f) + cy (16 f)

typedef __attribute__((ext_vector_type(8))) short v8s;   // 8 x bf16 (MFMA A/B frag)
typedef __attribute__((ext_vector_type(4))) float v4f;   // 4 x f32 (MFMA C/D frag)

__device__ __forceinline__ unsigned short f2bf(float f) {
    unsigned int u = __float_as_uint(f);
    u = u + 0x7FFFu + ((u >> 16) & 1u);   // round-to-nearest-even
    return (unsigned short)(u >> 16);
}
__device__ __forceinline__ float bf2f(unsigned short s) {
    return __uint_as_float(((unsigned int)s) << 16);
}

// ---------------------------------------------------------------------------
// K1: per-(batch, t-segment) partial Gram G += Hseg Hseg^T (34x34) and s0.
// bf16 hi/lo split MFMA: G = Hh Hh^T + Hh Hl^T + Hl Hh^T  (~fp32 accuracy)
// grid = 512 batches x 4 segments; partials combined via global atomicAdd.
// LDS row stride 152 shorts: 304B (16B-aligned for ds_read_b128), 76 words
// == 12 mod 32 -> 8-row bank cycle, no 8-way scatter-write conflicts.
// ---------------------------------------------------------------------------
struct SmemGramA {
    unsigned short Hh[48][152];
    unsigned short Hl[48][152];
};
struct SmemGramB {
    float Gpart[4][34][36];
    float spart[4][36];
};

__global__ __launch_bounds__(256) void k_gram(const float* __restrict__ x,
                                              float* __restrict__ ws) {
    __shared__ union { SmemGramA a; SmemGramB b; } sm;

    const int b    = blockIdx.x >> 2;
    const int seg  = blockIdx.x & 3;          // 4 segments of 512 t
    const int tid  = threadIdx.x;
    const int l    = tid & 63;
    const int w    = tid >> 6;                // wave id 0..3 -> k-slice in chunk
    const int row16 = l & 15;
    const int quad  = l >> 4;
    const float* xb = x + (size_t)b * XB;

    v4f accG[3][3];
    v4f accS[3];
    v4f vz = {0.f, 0.f, 0.f, 0.f};
#pragma unroll
    for (int r = 0; r < 3; ++r) {
        accS[r] = vz;
#pragma unroll
        for (int c = 0; c < 3; ++c) accG[r][c] = vz;
    }
    v8s ones;
#pragma unroll
    for (int i = 0; i < 8; ++i) ones[i] = (short)0x3F80;   // bf16 1.0

    for (int ch = 0; ch < 4; ++ch) {          // 4 chunks of 128 t
        const int t0 = seg * 512 + ch * 128;
        __syncthreads();
        // stage chunk: x[b,co,t,v] -> H[co*17+v][t_local], bf16 hi/lo, float4 loads
        for (int i = tid; i < 1088; i += 256) {
            int co = (i >= 544);
            int j4 = i - co * 544;
            const float4 f4 = *(const float4*)(xb + co * XC + t0 * 17 + j4 * 4);
            const float fv[4] = {f4.x, f4.y, f4.z, f4.w};
#pragma unroll
            for (int e = 0; e < 4; ++e) {
                int j = j4 * 4 + e;
                int t = j / 17;
                int v = j - t * 17;
                float f = fv[e];
                unsigned short hb = f2bf(f);
                sm.a.Hh[co * 17 + v][t] = hb;
                sm.a.Hl[co * 17 + v][t] = f2bf(f - bf2f(hb));
            }
        }
        __syncthreads();
        // wave w handles k-slice [w*32, w*32+32)
        const int koff = w * 32 + quad * 8;
        v8s fh[3], fl4[3];
#pragma unroll
        for (int r = 0; r < 3; ++r) {
            fh[r]  = *(const v8s*)&sm.a.Hh[r * 16 + row16][koff];
            fl4[r] = *(const v8s*)&sm.a.Hl[r * 16 + row16][koff];
        }
#pragma unroll
        for (int r = 0; r < 3; ++r) {
#pragma unroll
            for (int c = 0; c < 3; ++c) {
                accG[r][c] = __builtin_amdgcn_mfma_f32_16x16x32_bf16(fh[r],  fh[c],  accG[r][c], 0, 0, 0);
                accG[r][c] = __builtin_amdgcn_mfma_f32_16x16x32_bf16(fh[r],  fl4[c], accG[r][c], 0, 0, 0);
                accG[r][c] = __builtin_amdgcn_mfma_f32_16x16x32_bf16(fl4[r], fh[c],  accG[r][c], 0, 0, 0);
            }
            accS[r] = __builtin_amdgcn_mfma_f32_16x16x32_bf16(fh[r],  ones, accS[r], 0, 0, 0);
            accS[r] = __builtin_amdgcn_mfma_f32_16x16x32_bf16(fl4[r], ones, accS[r], 0, 0, 0);
        }
    }

    __syncthreads();   // done reading sm.a — switch union to sm.b
    // write per-wave partials (D layout: row = quad*4+i, col = lane&15)
#pragma unroll
    for (int r = 0; r < 3; ++r) {
#pragma unroll
        for (int c = 0; c < 3; ++c) {
#pragma unroll
            for (int i = 0; i < 4; ++i) {
                int m = r * 16 + quad * 4 + i;
                int n = c * 16 + row16;
                if (m < 34 && n < 34) sm.b.Gpart[w][m][n] = accG[r][c][i];
            }
        }
        if (row16 == 0) {
#pragma unroll
            for (int i = 0; i < 4; ++i) {
                int m = r * 16 + quad * 4 + i;
                if (m < 34) sm.b.spart[w][m] = accS[r][i];
            }
        }
    }
    __syncthreads();
    float* gout = ws + (size_t)b * GS_STRIDE;
    for (int idx = tid; idx < 1156; idx += 256) {
        int m = idx / 34, n = idx - m * 34;
        atomicAdd(&gout[idx], sm.b.Gpart[0][m][n] + sm.b.Gpart[1][m][n] +
                              sm.b.Gpart[2][m][n] + sm.b.Gpart[3][m][n]);
    }
    if (tid < 34)
        atomicAdd(&gout[1156 + tid], sm.b.spart[0][tid] + sm.b.spart[1][tid] +
                                     sm.b.spart[2][tid] + sm.b.spart[3][tid]);
}

// ---------------------------------------------------------------------------
// K2: per-batch affine chain through 3 attention layers + BN-folded head.
// All matmuls are C[i][j] = sum_e L[i][e]*R[j][e] on 36-padded LDS tiles.
// ---------------------------------------------------------------------------
__device__ void mm(float L[][36], float R[][36], float D[][36], int tid) {
    if (tid < 81) {
        int ti = tid / 9, tj = tid - ti * 9;
        int i0 = ti * 4, j0 = tj * 4;
        float acc[4][4] = {};
        for (int e0 = 0; e0 < 36; e0 += 4) {
            float4 lv[4], rv[4];
#pragma unroll
            for (int a = 0; a < 4; ++a) {
                lv[a] = *(const float4*)&L[i0 + a][e0];
                rv[a] = *(const float4*)&R[j0 + a][e0];
            }
#pragma unroll
            for (int a = 0; a < 4; ++a)
#pragma unroll
                for (int c = 0; c < 4; ++c)
                    acc[a][c] += lv[a].x * rv[c].x + lv[a].y * rv[c].y +
                                 lv[a].z * rv[c].z + lv[a].w * rv[c].w;
        }
#pragma unroll
        for (int a = 0; a < 4; ++a)
#pragma unroll
            for (int c = 0; c < 4; ++c)
                D[i0 + a][j0 + c] = acc[a][c];
    }
}

__global__ __launch_bounds__(128) void k_chain(
    const float* __restrict__ wq, const float* __restrict__ bq,
    const float* __restrict__ wk, const float* __restrict__ bk,
    const float* __restrict__ wv, const float* __restrict__ bv,
    const float* __restrict__ w1, const float* __restrict__ b1,
    const float* __restrict__ gamma, const float* __restrict__ beta,
    const float* __restrict__ mean, const float* __restrict__ var,
    float* __restrict__ ws) {
    __shared__ float G0b[36][36], At[36][36], Aq[36][36], Ak[36][36], Av[36][36],
        Avt[36][36], S1[36][36], Sc[36][36], Wq[36][36], Wk[36][36], Wv[36][36];
    __shared__ float s0v[36], a_[36], aq_[36], ak_[36], avv_[36], qs_[36], ks_[36],
        bqv[36], bkv[36], bvv[36], invv[16];

    const int tid = threadIdx.x;
    const int b   = blockIdx.x;
    const float* gsb = ws + (size_t)b * GS_STRIDE;

    for (int i = tid; i < 36 * 36; i += 128) {
        ((float*)G0b)[i] = 0; ((float*)At)[i] = 0; ((float*)Aq)[i] = 0;
        ((float*)Ak)[i] = 0;  ((float*)Av)[i] = 0; ((float*)Avt)[i] = 0;
        ((float*)S1)[i] = 0;  ((float*)Sc)[i] = 0; ((float*)Wq)[i] = 0;
        ((float*)Wk)[i] = 0;  ((float*)Wv)[i] = 0;
    }
    if (tid < 36) {
        s0v[tid] = 0; a_[tid] = 0; aq_[tid] = 0; ak_[tid] = 0; avv_[tid] = 0;
        qs_[tid] = 0; ks_[tid] = 0; bqv[tid] = 0; bkv[tid] = 0; bvv[tid] = 0;
    }
    __syncthreads();
    for (int i = tid; i < 1156; i += 128) {
        int m = i / 34;
        G0b[m][i - m * 34] = gsb[i];
    }
    if (tid < 34) {
        s0v[tid] = gsb[1156 + tid];
        At[tid][tid] = 1.0f;          // A = I (At = A^T)
    }

    for (int lyr = 0; lyr < 3; ++lyr) {
        __syncthreads();
        const float* wql = wq + lyr * 1156;
        const float* wkl = wk + lyr * 1156;
        const float* wvl = wv + lyr * 1156;
        for (int i = tid; i < 1156; i += 128) {
            int m = i / 34, n = i - m * 34;
            Wq[m][n] = wql[i]; Wk[m][n] = wkl[i]; Wv[m][n] = wvl[i];
        }
        if (tid < 34) {
            bqv[tid] = bq[lyr * 34 + tid];
            bkv[tid] = bk[lyr * 34 + tid];
            bvv[tid] = bv[lyr * 34 + tid];
        }
        __syncthreads();
        mm(Wq, At, Aq, tid);   // Aq[o][c] = (wq A)[o][c]
        mm(Wk, At, Ak, tid);
        mm(Wv, At, Av, tid);
        __syncthreads();
        for (int i = tid; i < 1296; i += 128) {
            int m = i / 36, n = i - m * 36;
            Avt[m][n] = Av[n][m];
        }
        if (tid < 34) {
            float x1 = 0, x2 = 0, x3 = 0;
            for (int e = 0; e < 34; ++e) {
                x1 += Wq[tid][e] * a_[e];
                x2 += Wk[tid][e] * a_[e];
                x3 += Wv[tid][e] * a_[e];
            }
            aq_[tid]  = x1 + bqv[tid];
            ak_[tid]  = x2 + bkv[tid];
            avv_[tid] = x3 + bvv[tid];
            float y1 = 0, y2 = 0;
            for (int e = 0; e < 34; ++e) {
                y1 += Aq[tid][e] * s0v[e];
                y2 += Ak[tid][e] * s0v[e];
            }
            qs_[tid] = y1; ks_[tid] = y2;
        }
        __syncthreads();
        mm(Aq, G0b, S1, tid);    // S1 = Aq G0 (G0 symmetric)
        __syncthreads();
        mm(S1, Ak, Sc, tid);     // Sc = Aq G0 Ak^T
        __syncthreads();
        if (tid < 34) {
            const int c = tid;
            const float scale = 0.022097086912079608f;   // 1/sqrt(2048)
            float mx = -1e30f;
            for (int d = 0; d < 34; ++d) {
                float v = (Sc[c][d] + qs_[c] * ak_[d] + aq_[c] * ks_[d] +
                           2048.0f * aq_[c] * ak_[d]) * scale;
                Sc[c][d] = v;
                mx = fmaxf(mx, v);
            }
            float sum = 0;
            for (int d = 0; d < 34; ++d) {
                float e = __expf(Sc[c][d] - mx);
                Sc[c][d] = e;
                sum += e;
            }
            float rs = 1.0f / sum;
            for (int d = 0; d < 34; ++d) Sc[c][d] *= rs;
        }
        __syncthreads();
        mm(Avt, Sc, At, tid);    // At_new[j][c] = sum_d Av[d][j] attn[c][d]
        if (tid < 34) {
            float s = 0;
            for (int d = 0; d < 34; ++d) s += Sc[tid][d] * avv_[d];
            a_[tid] = s;
        }
    }
    __syncthreads();
    // head: Wy = w1 * A3, fold BN
    for (int i = tid; i < 1296; i += 128) {
        int m = i / 36, n = i - m * 36;
        Wq[m][n] = (m < 16 && n < 34) ? w1[m * 34 + n] : 0.0f;
    }
    if (tid < 16) invv[tid] = gamma[tid] * rsqrtf(var[tid] + 1e-5f);
    __syncthreads();
    mm(Wq, At, S1, tid);         // S1[o][c] = Wy
    __syncthreads();
    float* wb = ws + RB_OFF + (size_t)b * RB_STRIDE;
    if (tid < 16) {
        float cy = 0;
        for (int e = 0; e < 34; ++e) cy += Wq[tid][e] * a_[e];
        cy += b1[tid];
        wb[1024 + tid] = (cy - mean[tid]) * invv[tid] + beta[tid];
    }
    unsigned short* wp = (unsigned short*)wb;
    for (int i = tid; i < 1024; i += 128) {
        int o = i >> 6, c = i & 63;
        float vv = (c < 34) ? S1[o][c] * invv[o] : 0.0f;
        unsigned short hb = f2bf(vv);
        wp[i] = hb;
        wp[1024 + i] = f2bf(vv - bf2f(hb));
    }
}

// ---------------------------------------------------------------------------
// K3: out = w2 * leaky(Wy' h0 + cy') + b2, streaming over t via MFMA.
// grid = 512 batches x 8 segments (256 t each, 2 chunks of 128 t).
// LDS h^T rows padded to 72 shorts (144B, 16B-aligned; 36-word stride walks
// banks by 4 per t-row -> scatter writes ~2-way instead of 4-way+).
// ---------------------------------------------------------------------------
__global__ __launch_bounds__(256) void k_out(const float* __restrict__ x,
                                             const float* __restrict__ w2,
                                             const float* __restrict__ b2,
                                             const float* __restrict__ ws,
                                             float* __restrict__ out) {
    __shared__ unsigned short HtH[128][72];   // h^T rows = t, cols = channel
    __shared__ unsigned short HtL[128][72];

    const int tid  = threadIdx.x;
    const int b    = blockIdx.x >> 3;
    const int seg  = (blockIdx.x & 7) * 256;
    const int l    = tid & 63;
    const int w    = tid >> 6;
    const int quad = l >> 4;
    const int col  = l & 15;

    const float* wb = ws + RB_OFF + (size_t)b * RB_STRIDE;
    const unsigned short* wp = (const unsigned short*)wb;
    v8s aH[2], aL[2];   // Wy A-frags: A[m=lane&15][k=quad*8+j], 2 k-steps
#pragma unroll
    for (int ks = 0; ks < 2; ++ks) {
        aH[ks] = *(const v8s*)&wp[col * 64 + ks * 32 + quad * 8];
        aL[ks] = *(const v8s*)&wp[1024 + col * 64 + ks * 32 + quad * 8];
    }
    float cyr[4], w2r[3][4];
#pragma unroll
    for (int i = 0; i < 4; ++i) {
        int o = quad * 4 + i;
        cyr[i] = wb[1024 + o];
#pragma unroll
        for (int p = 0; p < 3; ++p) w2r[p][i] = w2[p * 16 + o];
    }
    float b2r[3] = {b2[0], b2[1], b2[2]};
    const float* xb = x + (size_t)b * XB;

    // zero channel pad cols 34..63 once (frag reads only touch cols < 64)
    for (int idx = tid; idx < 128 * 30; idx += 256) {
        int t = idx / 30;
        int c = 34 + (idx - t * 30);
        HtH[t][c] = 0;
        HtL[t][c] = 0;
    }

    for (int ch = 0; ch < 2; ++ch) {
        const int t0c = seg + ch * 128;
        __syncthreads();
        for (int i = tid; i < 1088; i += 256) {
            int co = (i >= 544);
            int j4 = i - co * 544;
            const float4 f4 = *(const float4*)(xb + co * XC + t0c * 17 + j4 * 4);
            const float fv[4] = {f4.x, f4.y, f4.z, f4.w};
#pragma unroll
            for (int e = 0; e < 4; ++e) {
                int j = j4 * 4 + e;
                int t = j / 17;
                int v = j - t * 17;
                float f = fv[e];
                unsigned short hb = f2bf(f);
                HtH[t][co * 17 + v] = hb;
                HtL[t][co * 17 + v] = f2bf(f - bf2f(hb));
            }
        }
        __syncthreads();
        for (int tt = w; tt < 8; tt += 4) {       // 8 t-tiles of 16, wave-strided
            const int tBase = tt * 16;
            v4f acc = {0.f, 0.f, 0.f, 0.f};
#pragma unroll
            for (int ks = 0; ks < 2; ++ks) {
                v8s bH = *(const v8s*)&HtH[tBase + col][ks * 32 + quad * 8];
                v8s bL = *(const v8s*)&HtL[tBase + col][ks * 32 + quad * 8];
                acc = __builtin_amdgcn_mfma_f32_16x16x32_bf16(aH[ks], bH, acc, 0, 0, 0);
                acc = __builtin_amdgcn_mfma_f32_16x16x32_bf16(aH[ks], bL, acc, 0, 0, 0);
                acc = __builtin_amdgcn_mfma_f32_16x16x32_bf16(aL[ks], bH, acc, 0, 0, 0);
            }
            // epilogue: y -> leaky -> partial w2 dot (4 o's per lane)
            float op[3] = {0, 0, 0};
#pragma unroll
            for (int i = 0; i < 4; ++i) {
                float y = acc[i] + cyr[i];
                float z = (y > 0.f) ? y : 0.01f * y;
#pragma unroll
                for (int p = 0; p < 3; ++p) op[p] += w2r[p][i] * z;
            }
#pragma unroll
            for (int p = 0; p < 3; ++p) {
                op[p] += __shfl_xor(op[p], 16);
                op[p] += __shfl_xor(op[p], 32);
            }
            if (l < 16) {
                int tg = t0c + tBase + l;
#pragma unroll
                for (int p = 0; p < 3; ++p)
                    out[((size_t)b * 3 + p) * 2048 + tg] = op[p] + b2r[p];
            }
        }
    }
}

extern "C" void kernel_launch(void* const* d_in, const int* in_sizes, int n_in,
                              void* d_out, int out_size, void* d_ws, size_t ws_size,
                              hipStream_t stream) {
    const float* x     = (const float*)d_in[0];
    const float* wq    = (const float*)d_in[1];
    const float* bq    = (const float*)d_in[2];
    const float* wk    = (const float*)d_in[3];
    const float* bk    = (const float*)d_in[4];
    const float* wv    = (const float*)d_in[5];
    const float* bv    = (const float*)d_in[6];
    const float* w1    = (const float*)d_in[7];
    const float* b1    = (const float*)d_in[8];
    const float* gamma = (const float*)d_in[9];
    const float* beta  = (const float*)d_in[10];
    const float* mean  = (const float*)d_in[11];
    const float* var   = (const float*)d_in[12];
    const float* w2    = (const float*)d_in[13];
    const float* b2    = (const float*)d_in[14];
    float* ws  = (float*)d_ws;
    float* out = (float*)d_out;

    // zero region A (per-batch G accumulators) — k_gram atomicAdds into it
    hipMemsetAsync(d_ws, 0, (size_t)NB * GS_STRIDE * sizeof(float), stream);
    k_gram<<<dim3(2048), dim3(256), 0, stream>>>(x, ws);
    k_chain<<<dim3(512), dim3(128), 0, stream>>>(wq, bq, wk, bk, wv, bv,
                                                 w1, b1, gamma, beta, mean, var, ws);
    k_out<<<dim3(4096), dim3(256), 0, stream>>>(x, w2, b2, ws, out);
}

// Round 3
// 333.799 us; speedup vs baseline: 1.4332x; 1.0879x over previous
//
#include <hip/hip_runtime.h>

// Problem constants
#define CV   34          // C*V channels
#define TTOT 2048        // T
#define NB   512         // batches
#define XB   69632       // x per-batch stride (2*2048*17)
#define XC   34816       // x per-co stride (2048*17)

// Workspace layout (floats)
#define GS_STRIDE 1192                   // per-batch: G (1156) + s0 (34) + pad
#define RB_OFF    (512 * 1192)           // region B offset
#define RB_STRIDE 1040                   // per-batch: Wy bf16 hi/lo planes (1024 f) + cy (16 f)

typedef __attribute__((ext_vector_type(8))) short v8s;   // 8 x bf16 (MFMA A/B frag)
typedef __attribute__((ext_vector_type(4))) float v4f;   // 4 x f32 (MFMA C/D frag)

__device__ __forceinline__ unsigned short f2bf(float f) {
    unsigned int u = __float_as_uint(f);
    u = u + 0x7FFFu + ((u >> 16) & 1u);   // round-to-nearest-even
    return (unsigned short)(u >> 16);
}
__device__ __forceinline__ float bf2f(unsigned short s) {
    return __uint_as_float(((unsigned int)s) << 16);
}

// ---------------------------------------------------------------------------
// K1: per-(batch, t-segment) partial Gram G += Hseg Hseg^T (34x34) and s0.
// (unchanged from round 2)
// ---------------------------------------------------------------------------
struct SmemGramA {
    unsigned short Hh[48][152];
    unsigned short Hl[48][152];
};
struct SmemGramB {
    float Gpart[4][34][36];
    float spart[4][36];
};

__global__ __launch_bounds__(256) void k_gram(const float* __restrict__ x,
                                              float* __restrict__ ws) {
    __shared__ union { SmemGramA a; SmemGramB b; } sm;

    const int b    = blockIdx.x >> 2;
    const int seg  = blockIdx.x & 3;          // 4 segments of 512 t
    const int tid  = threadIdx.x;
    const int l    = tid & 63;
    const int w    = tid >> 6;                // wave id 0..3 -> k-slice in chunk
    const int row16 = l & 15;
    const int quad  = l >> 4;
    const float* xb = x + (size_t)b * XB;

    v4f accG[3][3];
    v4f accS[3];
    v4f vz = {0.f, 0.f, 0.f, 0.f};
#pragma unroll
    for (int r = 0; r < 3; ++r) {
        accS[r] = vz;
#pragma unroll
        for (int c = 0; c < 3; ++c) accG[r][c] = vz;
    }
    v8s ones;
#pragma unroll
    for (int i = 0; i < 8; ++i) ones[i] = (short)0x3F80;   // bf16 1.0

    for (int ch = 0; ch < 4; ++ch) {          // 4 chunks of 128 t
        const int t0 = seg * 512 + ch * 128;
        __syncthreads();
        for (int i = tid; i < 1088; i += 256) {
            int co = (i >= 544);
            int j4 = i - co * 544;
            const float4 f4 = *(const float4*)(xb + co * XC + t0 * 17 + j4 * 4);
            const float fv[4] = {f4.x, f4.y, f4.z, f4.w};
#pragma unroll
            for (int e = 0; e < 4; ++e) {
                int j = j4 * 4 + e;
                int t = j / 17;
                int v = j - t * 17;
                float f = fv[e];
                unsigned short hb = f2bf(f);
                sm.a.Hh[co * 17 + v][t] = hb;
                sm.a.Hl[co * 17 + v][t] = f2bf(f - bf2f(hb));
            }
        }
        __syncthreads();
        const int koff = w * 32 + quad * 8;
        v8s fh[3], fl4[3];
#pragma unroll
        for (int r = 0; r < 3; ++r) {
            fh[r]  = *(const v8s*)&sm.a.Hh[r * 16 + row16][koff];
            fl4[r] = *(const v8s*)&sm.a.Hl[r * 16 + row16][koff];
        }
#pragma unroll
        for (int r = 0; r < 3; ++r) {
#pragma unroll
            for (int c = 0; c < 3; ++c) {
                accG[r][c] = __builtin_amdgcn_mfma_f32_16x16x32_bf16(fh[r],  fh[c],  accG[r][c], 0, 0, 0);
                accG[r][c] = __builtin_amdgcn_mfma_f32_16x16x32_bf16(fh[r],  fl4[c], accG[r][c], 0, 0, 0);
                accG[r][c] = __builtin_amdgcn_mfma_f32_16x16x32_bf16(fl4[r], fh[c],  accG[r][c], 0, 0, 0);
            }
            accS[r] = __builtin_amdgcn_mfma_f32_16x16x32_bf16(fh[r],  ones, accS[r], 0, 0, 0);
            accS[r] = __builtin_amdgcn_mfma_f32_16x16x32_bf16(fl4[r], ones, accS[r], 0, 0, 0);
        }
    }

    __syncthreads();   // done reading sm.a — switch union to sm.b
#pragma unroll
    for (int r = 0; r < 3; ++r) {
#pragma unroll
        for (int c = 0; c < 3; ++c) {
#pragma unroll
            for (int i = 0; i < 4; ++i) {
                int m = r * 16 + quad * 4 + i;
                int n = c * 16 + row16;
                if (m < 34 && n < 34) sm.b.Gpart[w][m][n] = accG[r][c][i];
            }
        }
        if (row16 == 0) {
#pragma unroll
            for (int i = 0; i < 4; ++i) {
                int m = r * 16 + quad * 4 + i;
                if (m < 34) sm.b.spart[w][m] = accS[r][i];
            }
        }
    }
    __syncthreads();
    float* gout = ws + (size_t)b * GS_STRIDE;
    for (int idx = tid; idx < 1156; idx += 256) {
        int m = idx / 34, n = idx - m * 34;
        atomicAdd(&gout[idx], sm.b.Gpart[0][m][n] + sm.b.Gpart[1][m][n] +
                              sm.b.Gpart[2][m][n] + sm.b.Gpart[3][m][n]);
    }
    if (tid < 34)
        atomicAdd(&gout[1156 + tid], sm.b.spart[0][tid] + sm.b.spart[1][tid] +
                                     sm.b.spart[2][tid] + sm.b.spart[3][tid]);
}

// ---------------------------------------------------------------------------
// K2: per-batch affine chain. Rewritten for occupancy + stage concurrency:
// 256 threads, 7 LDS arrays (37 KB -> 4 blocks/CU), QKV mms concurrent,
// weights read from global (L1/L2-hot), Av written transposed at produce time,
// aux dot-products ride on idle threads of mm stages. 5 barriers/layer.
// ---------------------------------------------------------------------------

// 2x4-tile mm on LDS: D[i][j] = sum_e L[i][e]*R[j][e], 153 threads, K=36 (pads zero)
__device__ __forceinline__ void mm24(const float L[][36], const float R[][36],
                                     float D[][36], int u) {
    int ti = u / 9, tj = u - ti * 9;      // u < 153
    int i0 = ti * 2, j0 = tj * 4;
    float acc[2][4] = {};
    for (int e0 = 0; e0 < 36; e0 += 4) {
        float4 lv[2], rv[4];
        lv[0] = *(const float4*)&L[i0][e0];
        lv[1] = *(const float4*)&L[i0 + 1][e0];
#pragma unroll
        for (int c = 0; c < 4; ++c) rv[c] = *(const float4*)&R[j0 + c][e0];
#pragma unroll
        for (int a = 0; a < 2; ++a)
#pragma unroll
            for (int c = 0; c < 4; ++c)
                acc[a][c] += lv[a].x * rv[c].x + lv[a].y * rv[c].y +
                             lv[a].z * rv[c].z + lv[a].w * rv[c].w;
    }
#pragma unroll
    for (int a = 0; a < 2; ++a)
#pragma unroll
        for (int c = 0; c < 4; ++c) D[i0 + a][j0 + c] = acc[a][c];
}

// 4x4-tile mm, L from global (row stride 34, K=34), 81 threads.
// transpose=0: D[i][j] = sum_e Lg[i][e]*R[j][e]; transpose=1: D[j][i] = ...
__device__ __forceinline__ void mmG4(const float* __restrict__ Lg,
                                     const float R[][36], float D[][36],
                                     int transpose, int u) {
    int ti = u / 9, tj = u - ti * 9;      // u < 81
    int i0 = ti * 4, j0 = tj * 4;
    float acc[4][4] = {};
    for (int e0 = 0; e0 < 32; e0 += 4) {
        float2 la[4], lb[4];
        float4 rv[4];
#pragma unroll
        for (int a = 0; a < 4; ++a) {
            int ri = i0 + a; ri = ri < 34 ? ri : 33;   // clamp: row 34/35 loads
            la[a] = *(const float2*)(Lg + ri * 34 + e0);
            lb[a] = *(const float2*)(Lg + ri * 34 + e0 + 2);
        }
#pragma unroll
        for (int c = 0; c < 4; ++c) rv[c] = *(const float4*)&R[j0 + c][e0];
#pragma unroll
        for (int a = 0; a < 4; ++a)
#pragma unroll
            for (int c = 0; c < 4; ++c)
                acc[a][c] += la[a].x * rv[c].x + la[a].y * rv[c].y +
                             lb[a].x * rv[c].z + lb[a].y * rv[c].w;
    }
    {   // tail e = 32,33
        float2 la[4];
#pragma unroll
        for (int a = 0; a < 4; ++a) {
            int ri = i0 + a; ri = ri < 34 ? ri : 33;
            la[a] = *(const float2*)(Lg + ri * 34 + 32);
        }
#pragma unroll
        for (int c = 0; c < 4; ++c) {
            float r0 = R[j0 + c][32], r1 = R[j0 + c][33];
#pragma unroll
            for (int a = 0; a < 4; ++a) acc[a][c] += la[a].x * r0 + la[a].y * r1;
        }
    }
#pragma unroll
    for (int a = 0; a < 4; ++a) {
        if (i0 + a < 34) {
#pragma unroll
            for (int c = 0; c < 4; ++c) {
                if (transpose) D[j0 + c][i0 + a] = acc[a][c];
                else           D[i0 + a][j0 + c] = acc[a][c];
            }
        }
    }
}

__global__ __launch_bounds__(256) void k_chain(
    const float* __restrict__ wq, const float* __restrict__ bq,
    const float* __restrict__ wk, const float* __restrict__ bk,
    const float* __restrict__ wv, const float* __restrict__ bv,
    const float* __restrict__ w1, const float* __restrict__ b1,
    const float* __restrict__ gamma, const float* __restrict__ beta,
    const float* __restrict__ mean, const float* __restrict__ var,
    float* __restrict__ ws) {
    __shared__ float G0b[36][36], At[36][36], Aq[36][36], Ak[36][36],
        AvT[36][36], S1[36][36], Sc[36][36];
    __shared__ float s0v[36], a_[36], aq_[36], ak_[36], avv_[36],
        qs_[36], ks_[36], invv[16];

    const int tid = threadIdx.x;
    const int b   = blockIdx.x;
    const float* gsb = ws + (size_t)b * GS_STRIDE;

    // zero all LDS (pads must be 0 and stay 0)
    for (int i = tid; i < 1296; i += 256) {
        int m = i / 36, n = i - m * 36;
        G0b[m][n] = 0; At[m][n] = 0; Aq[m][n] = 0; Ak[m][n] = 0;
        AvT[m][n] = 0; S1[m][n] = 0; Sc[m][n] = 0;
    }
    if (tid < 36) {
        s0v[tid] = 0; a_[tid] = 0; aq_[tid] = 0; ak_[tid] = 0; avv_[tid] = 0;
        qs_[tid] = 0; ks_[tid] = 0;
    }
    __syncthreads();
    // load G0, s0; layer-0 shortcut: A = I  =>  Aq=wq0, Ak=wk0, AvT=wv0^T, aux=b*
    for (int i = tid; i < 1156; i += 256) {
        int m = i / 34, n = i - m * 34;
        G0b[m][n] = gsb[i];
        Aq[m][n] = wq[i]; Ak[m][n] = wk[i]; AvT[n][m] = wv[i];
    }
    if (tid < 34) {
        s0v[tid] = gsb[1156 + tid];
        aq_[tid] = bq[tid]; ak_[tid] = bk[tid]; avv_[tid] = bv[tid];
    }
    __syncthreads();

    for (int lyr = 0; lyr < 3; ++lyr) {
        const float* wql = wq + lyr * 1156;
        const float* wkl = wk + lyr * 1156;
        const float* wvl = wv + lyr * 1156;
        if (lyr > 0) {
            // stage1: Aq = Wq*A, Ak = Wk*A, AvT = (Wv*A)^T  (concurrent)
            if (tid < 243) {
                int g = tid / 81, u = tid - g * 81;
                const float* Lg = (g == 0) ? wql : (g == 1) ? wkl : wvl;
                float (*D)[36] = (g == 0) ? Aq : (g == 1) ? Ak : AvT;
                mmG4(Lg, At, D, g == 2, u);
            }
            __syncthreads();
        }
        // stage2: S1 = Aq*G0 ; aux1: aq_/ak_/avv_ = w*a_ + b  (skip for lyr 0)
        if (tid < 153) {
            mm24(Aq, G0b, S1, tid);
        } else if (lyr > 0 && tid < 255) {
            int u = tid - 153, r = u / 34, c = u - r * 34;
            const float* wrow = ((r == 0) ? wql : (r == 1) ? wkl : wvl) + c * 34;
            float s = 0;
            for (int e = 0; e < 34; ++e) s += wrow[e] * a_[e];
            float bb = (r == 0) ? bq[lyr * 34 + c]
                     : (r == 1) ? bk[lyr * 34 + c] : bv[lyr * 34 + c];
            if (r == 0) aq_[c] = s + bb;
            else if (r == 1) ak_[c] = s + bb;
            else avv_[c] = s + bb;
        }
        __syncthreads();
        // stage3: Sc = S1*Ak^T ; qs_ = Aq*s0, ks_ = Ak*s0
        if (tid < 153) {
            mm24(S1, Ak, Sc, tid);
        } else if (tid >= 160 && tid < 228) {
            int u = tid - 160, r = u / 34, c = u - r * 34;
            const float (*M)[36] = r ? Ak : Aq;
            float s = 0;
            for (int e = 0; e < 34; ++e) s += M[c][e] * s0v[e];
            if (r == 0) qs_[c] = s; else ks_[c] = s;
        }
        __syncthreads();
        // stage4: softmax rows (with rank-1 score corrections)
        if (tid < 34) {
            const int c = tid;
            const float scale = 0.022097086912079608f;   // 1/sqrt(2048)
            float mx = -1e30f;
            for (int d = 0; d < 34; ++d) {
                float v = (Sc[c][d] + qs_[c] * ak_[d] + aq_[c] * ks_[d] +
                           2048.0f * aq_[c] * ak_[d]) * scale;
                Sc[c][d] = v;
                mx = fmaxf(mx, v);
            }
            float sum = 0;
            for (int d = 0; d < 34; ++d) {
                float e = __expf(Sc[c][d] - mx);
                Sc[c][d] = e;
                sum += e;
            }
            float rs = 1.0f / sum;
            for (int d = 0; d < 34; ++d) Sc[c][d] *= rs;
        }
        __syncthreads();
        // stage5: At = AvT * attn^T ; a_ = attn * avv_
        if (tid < 153) {
            mm24(AvT, Sc, At, tid);
        } else if (tid >= 160 && tid < 194) {
            int c = tid - 160;
            float s = 0;
            for (int d = 0; d < 34; ++d) s += Sc[c][d] * avv_[d];
            a_[c] = s;
        }
        __syncthreads();
    }

    // stage6: S1[o][c] = (w1 * A3)[o][c] (o<16) ; invv ; cy_raw -> ks_
    if (tid < 72) {
        int ti = tid / 9, tj = tid - ti * 9;
        int i0 = ti * 2, j0 = tj * 4;
        float acc[2][4] = {};
        for (int e0 = 0; e0 < 32; e0 += 4) {
            float2 la[2], lb[2];
            float4 rv[4];
#pragma unroll
            for (int a = 0; a < 2; ++a) {
                la[a] = *(const float2*)(w1 + (i0 + a) * 34 + e0);
                lb[a] = *(const float2*)(w1 + (i0 + a) * 34 + e0 + 2);
            }
#pragma unroll
            for (int c = 0; c < 4; ++c) rv[c] = *(const float4*)&At[j0 + c][e0];
#pragma unroll
            for (int a = 0; a < 2; ++a)
#pragma unroll
                for (int c = 0; c < 4; ++c)
                    acc[a][c] += la[a].x * rv[c].x + la[a].y * rv[c].y +
                                 lb[a].x * rv[c].z + lb[a].y * rv[c].w;
        }
        {
            float2 la[2];
#pragma unroll
            for (int a = 0; a < 2; ++a)
                la[a] = *(const float2*)(w1 + (i0 + a) * 34 + 32);
#pragma unroll
            for (int c = 0; c < 4; ++c) {
                float r0 = At[j0 + c][32], r1 = At[j0 + c][33];
#pragma unroll
                for (int a = 0; a < 2; ++a) acc[a][c] += la[a].x * r0 + la[a].y * r1;
            }
        }
#pragma unroll
        for (int a = 0; a < 2; ++a)
#pragma unroll
            for (int c = 0; c < 4; ++c) S1[i0 + a][j0 + c] = acc[a][c];
    } else if (tid < 88) {
        int o = tid - 72;
        invv[o] = gamma[o] * rsqrtf(var[o] + 1e-5f);
    } else if (tid < 104) {
        int o = tid - 88;
        float s = 0;
        for (int e = 0; e < 34; ++e) s += w1[o * 34 + e] * a_[e];
        ks_[o] = s + b1[o];          // raw cy
    }
    __syncthreads();
    // stage7: emit Wy' bf16 hi/lo planes + BN-folded cy'
    float* wb = ws + RB_OFF + (size_t)b * RB_STRIDE;
    if (tid < 16)
        wb[1024 + tid] = (ks_[tid] - mean[tid]) * invv[tid] + beta[tid];
    unsigned short* wp = (unsigned short*)wb;
    for (int i = tid; i < 1024; i += 256) {
        int o = i >> 6, c = i & 63;
        float vv = (c < 34) ? S1[o][c] * invv[o] : 0.0f;
        unsigned short hb = f2bf(vv);
        wp[i] = hb;
        wp[1024 + i] = f2bf(vv - bf2f(hb));
    }
}

// ---------------------------------------------------------------------------
// K3: out = w2 * leaky(Wy' h0 + cy') + b2  (unchanged from round 2)
// ---------------------------------------------------------------------------
__global__ __launch_bounds__(256) void k_out(const float* __restrict__ x,
                                             const float* __restrict__ w2,
                                             const float* __restrict__ b2,
                                             const float* __restrict__ ws,
                                             float* __restrict__ out) {
    __shared__ unsigned short HtH[128][72];
    __shared__ unsigned short HtL[128][72];

    const int tid  = threadIdx.x;
    const int b    = blockIdx.x >> 3;
    const int seg  = (blockIdx.x & 7) * 256;
    const int l    = tid & 63;
    const int w    = tid >> 6;
    const int quad = l >> 4;
    const int col  = l & 15;

    const float* wb = ws + RB_OFF + (size_t)b * RB_STRIDE;
    const unsigned short* wp = (const unsigned short*)wb;
    v8s aH[2], aL[2];
#pragma unroll
    for (int ks = 0; ks < 2; ++ks) {
        aH[ks] = *(const v8s*)&wp[col * 64 + ks * 32 + quad * 8];
        aL[ks] = *(const v8s*)&wp[1024 + col * 64 + ks * 32 + quad * 8];
    }
    float cyr[4], w2r[3][4];
#pragma unroll
    for (int i = 0; i < 4; ++i) {
        int o = quad * 4 + i;
        cyr[i] = wb[1024 + o];
#pragma unroll
        for (int p = 0; p < 3; ++p) w2r[p][i] = w2[p * 16 + o];
    }
    float b2r[3] = {b2[0], b2[1], b2[2]};
    const float* xb = x + (size_t)b * XB;

    for (int idx = tid; idx < 128 * 30; idx += 256) {
        int t = idx / 30;
        int c = 34 + (idx - t * 30);
        HtH[t][c] = 0;
        HtL[t][c] = 0;
    }

    for (int ch = 0; ch < 2; ++ch) {
        const int t0c = seg + ch * 128;
        __syncthreads();
        for (int i = tid; i < 1088; i += 256) {
            int co = (i >= 544);
            int j4 = i - co * 544;
            const float4 f4 = *(const float4*)(xb + co * XC + t0c * 17 + j4 * 4);
            const float fv[4] = {f4.x, f4.y, f4.z, f4.w};
#pragma unroll
            for (int e = 0; e < 4; ++e) {
                int j = j4 * 4 + e;
                int t = j / 17;
                int v = j - t * 17;
                float f = fv[e];
                unsigned short hb = f2bf(f);
                HtH[t][co * 17 + v] = hb;
                HtL[t][co * 17 + v] = f2bf(f - bf2f(hb));
            }
        }
        __syncthreads();
        for (int tt = w; tt < 8; tt += 4) {
            const int tBase = tt * 16;
            v4f acc = {0.f, 0.f, 0.f, 0.f};
#pragma unroll
            for (int ks = 0; ks < 2; ++ks) {
                v8s bH = *(const v8s*)&HtH[tBase + col][ks * 32 + quad * 8];
                v8s bL = *(const v8s*)&HtL[tBase + col][ks * 32 + quad * 8];
                acc = __builtin_amdgcn_mfma_f32_16x16x32_bf16(aH[ks], bH, acc, 0, 0, 0);
                acc = __builtin_amdgcn_mfma_f32_16x16x32_bf16(aH[ks], bL, acc, 0, 0, 0);
                acc = __builtin_amdgcn_mfma_f32_16x16x32_bf16(aL[ks], bH, acc, 0, 0, 0);
            }
            float op[3] = {0, 0, 0};
#pragma unroll
            for (int i = 0; i < 4; ++i) {
                float y = acc[i] + cyr[i];
                float z = (y > 0.f) ? y : 0.01f * y;
#pragma unroll
                for (int p = 0; p < 3; ++p) op[p] += w2r[p][i] * z;
            }
#pragma unroll
            for (int p = 0; p < 3; ++p) {
                op[p] += __shfl_xor(op[p], 16);
                op[p] += __shfl_xor(op[p], 32);
            }
            if (l < 16) {
                int tg = t0c + tBase + l;
#pragma unroll
                for (int p = 0; p < 3; ++p)
                    out[((size_t)b * 3 + p) * 2048 + tg] = op[p] + b2r[p];
            }
        }
    }
}

extern "C" void kernel_launch(void* const* d_in, const int* in_sizes, int n_in,
                              void* d_out, int out_size, void* d_ws, size_t ws_size,
                              hipStream_t stream) {
    const float* x     = (const float*)d_in[0];
    const float* wq    = (const float*)d_in[1];
    const float* bq    = (const float*)d_in[2];
    const float* wk    = (const float*)d_in[3];
    const float* bk    = (const float*)d_in[4];
    const float* wv    = (const float*)d_in[5];
    const float* bv    = (const float*)d_in[6];
    const float* w1    = (const float*)d_in[7];
    const float* b1    = (const float*)d_in[8];
    const float* gamma = (const float*)d_in[9];
    const float* beta  = (const float*)d_in[10];
    const float* mean  = (const float*)d_in[11];
    const float* var   = (const float*)d_in[12];
    const float* w2    = (const float*)d_in[13];
    const float* b2    = (const float*)d_in[14];
    float* ws  = (float*)d_ws;
    float* out = (float*)d_out;

    hipMemsetAsync(d_ws, 0, (size_t)NB * GS_STRIDE * sizeof(float), stream);
    k_gram<<<dim3(2048), dim3(256), 0, stream>>>(x, ws);
    k_chain<<<dim3(512), dim3(256), 0, stream>>>(wq, bq, wk, bk, wv, bv,
                                                 w1, b1, gamma, beta, mean, var, ws);
    k_out<<<dim3(4096), dim3(256), 0, stream>>>(x, w2, b2, ws, out);
}